// Round 1
// baseline (235.932 us; speedup 1.0000x reference)
//
#include <hip/hip_runtime.h>

// ---------------------------------------------------------------------------
// MultiHeadAttention forward, MI355X/gfx950.
// Pipeline: cvt(fp32->bf16) -> QKV proj (bf16 MFMA) -> flash attn -> out proj.
// ---------------------------------------------------------------------------

#define DEV static __device__ __forceinline__

typedef __attribute__((ext_vector_type(8))) short short8;
typedef __attribute__((ext_vector_type(4))) float f32x4;
typedef __attribute__((ext_vector_type(4))) unsigned short ushort4v;

#define SEQ   2048
#define BATCH 2
#define DM    1024
#define NH    16
#define DKH   64
#define MROWS (SEQ*BATCH)   // 4096

DEV unsigned short f2bf(float f) {
  union { float f; unsigned int u; } v; v.f = f;
  unsigned int u = v.u;
  return (unsigned short)((u + 0x7FFFu + ((u >> 16) & 1u)) >> 16);  // RNE
}

// async global->LDS, 16B per lane. Dest must be wave-uniform base (+lane*16 implicit).
DEV void async16(const void* g, void* l) {
  __builtin_amdgcn_global_load_lds(
      (const __attribute__((address_space(1))) unsigned int*)g,
      (__attribute__((address_space(3))) unsigned int*)l, 16, 0, 0);
}

// ---------------------------------------------------------------------------
// fp32 -> bf16 conversion, 7 tensors in one launch (grid.y = tensor id)
// ---------------------------------------------------------------------------
struct CvtArgs {
  const float* s[8];
  unsigned short* d[8];
  int n[8];
};

__global__ __launch_bounds__(256) void cvt_kernel(CvtArgs a) {
  const int t = blockIdx.y;
  const float* __restrict__ s = a.s[t];
  unsigned short* __restrict__ d = a.d[t];
  const int n = a.n[t];
  const int i = (blockIdx.x * 256 + threadIdx.x) * 4;
  if (i >= n) return;
  f32x4 f = *(const f32x4*)&s[i];
  ushort4v o;
  o[0] = f2bf(f[0]); o[1] = f2bf(f[1]); o[2] = f2bf(f[2]); o[3] = f2bf(f[3]);
  *(ushort4v*)&d[i] = o;
}

// mask-nonzero detector (mask is all zeros in this problem; keep general)
__global__ __launch_bounds__(256) void maskchk_kernel(const float* __restrict__ m, int n, int* flag) {
  int any = 0;
  const int stride = gridDim.x * 256 * 4;
  for (int i = (blockIdx.x * 256 + threadIdx.x) * 4; i < n; i += stride) {
    f32x4 v = *(const f32x4*)&m[i];
    any |= (v[0] != 0.f);
    any |= (v[1] != 0.f);
    any |= (v[2] != 0.f);
    any |= (v[3] != 0.f);
  }
  if (any) atomicOr(flag, 1);
}

// ---------------------------------------------------------------------------
// GEMM: C[M,N] = A[M,K] @ W[N,K]^T + bias.  128x128 tile, BK=64, 4 waves.
// A,W bf16 row-major (K contiguous).  m97-style single-buffer 2-barrier loop.
// ---------------------------------------------------------------------------
template <typename OutT>
DEV void gemm_body(const unsigned short* __restrict__ A,
                   const unsigned short* __restrict__ W,
                   const float* __restrict__ bias,
                   OutT* __restrict__ C,
                   unsigned short* As, unsigned short* Bs,
                   int M, int N, int K, int m0, int n0) {
  const int tid = threadIdx.x;
  const int lane = tid & 63;
  const int wid = tid >> 6;
  const int wr = wid >> 1, wc = wid & 1;   // 2x2 wave grid, 64x64 per wave
  const int sr = lane & 15, g = lane >> 4;

  f32x4 acc[4][4] = {};

  const int arow = tid >> 3;          // 0..31
  const int acol = (tid & 7) * 8;     // elem col within 64
  const size_t abase = (size_t)(m0 + arow) * K + acol;
  const size_t bbase = (size_t)(n0 + arow) * K + acol;

  for (int kt = 0; kt < K; kt += 64) {
#pragma unroll
    for (int j = 0; j < 4; ++j) {
      async16(A + abase + (size_t)j * 32 * K + kt, (char*)As + j * 4096 + wid * 1024);
      async16(W + bbase + (size_t)j * 32 * K + kt, (char*)Bs + j * 4096 + wid * 1024);
    }
    __syncthreads();   // drains vmcnt: LDS tiles ready
#pragma unroll
    for (int kk = 0; kk < 2; ++kk) {
      short8 af[4], bf[4];
#pragma unroll
      for (int mt = 0; mt < 4; ++mt)
        af[mt] = *(const short8*)&As[(wr * 64 + mt * 16 + sr) * 64 + kk * 32 + g * 8];
#pragma unroll
      for (int nt = 0; nt < 4; ++nt)
        bf[nt] = *(const short8*)&Bs[(wc * 64 + nt * 16 + sr) * 64 + kk * 32 + g * 8];
#pragma unroll
      for (int mt = 0; mt < 4; ++mt)
#pragma unroll
        for (int nt = 0; nt < 4; ++nt)
          acc[mt][nt] = __builtin_amdgcn_mfma_f32_16x16x32_bf16(af[mt], bf[nt], acc[mt][nt], 0, 0, 0);
    }
    __syncthreads();   // protect LDS before next staging
  }

  // epilogue: C/D layout row=(lane>>4)*4+reg, col=lane&15  [m89-verified]
#pragma unroll
  for (int nt = 0; nt < 4; ++nt) {
    const int col = n0 + wc * 64 + nt * 16 + sr;
    const float bv = bias[col];
#pragma unroll
    for (int mt = 0; mt < 4; ++mt) {
#pragma unroll
      for (int r = 0; r < 4; ++r) {
        const int row = m0 + wr * 64 + mt * 16 + g * 4 + r;
        const float val = acc[mt][nt][r] + bv;
        if constexpr (sizeof(OutT) == 2)
          C[(size_t)row * N + col] = f2bf(val);
        else
          C[(size_t)row * N + col] = val;
      }
    }
  }
}

struct GemmPtrs {
  const unsigned short* A[3];
  const unsigned short* W[3];
  const float* bias[3];
  unsigned short* C[3];
};

__global__ __launch_bounds__(256) void gemm_qkv_kernel(GemmPtrs p, int M, int N, int K) {
  __shared__ unsigned short As[128 * 64];
  __shared__ unsigned short Bs[128 * 64];
  const int z = blockIdx.z;
  gemm_body<unsigned short>(p.A[z], p.W[z], p.bias[z], p.C[z], As, Bs,
                            M, N, K, blockIdx.x * 128, blockIdx.y * 128);
}

__global__ __launch_bounds__(256) void gemm_f32_kernel(const unsigned short* __restrict__ A,
                                                       const unsigned short* __restrict__ W,
                                                       const float* __restrict__ bias,
                                                       float* __restrict__ C,
                                                       int M, int N, int K) {
  __shared__ unsigned short As[128 * 64];
  __shared__ unsigned short Bs[128 * 64];
  gemm_body<float>(A, W, bias, C, As, Bs, M, N, K, blockIdx.x * 128, blockIdx.y * 128);
}

// ---------------------------------------------------------------------------
// Flash attention.  Grid: (S/64, B*H).  256 thr = 4 waves, wave w owns q-rows
// [w*16, w*16+16).  KV tile = 64.  Layouts all (S, B, D) with d = h*64+dk.
// K LDS is XOR-swizzled (both-sides: pre-swizzled global src for
// global_load_lds + swizzled ds_read) to avoid a 16-way bank conflict.
// V transposed LDS->LDS into padded [64][72] Vt for the PV B-operand.
// ---------------------------------------------------------------------------
__global__ __launch_bounds__(256) void attn_kernel(const unsigned short* __restrict__ Q,
                                                   const unsigned short* __restrict__ K,
                                                   const unsigned short* __restrict__ V,
                                                   const float* __restrict__ mask,
                                                   const int* __restrict__ maskflag,
                                                   unsigned short* __restrict__ O) {
  __shared__ unsigned short Kl[64 * 64];      // swizzled rows of 128B
  __shared__ unsigned short Vlin[64 * 64];    // linear [t][d]
  __shared__ unsigned short Vt[64 * 72];      // [d][t], pad 72 (16B-aligned rows)
  __shared__ unsigned short Pl[4][16 * 72];   // per-wave P tile

  const int tid = threadIdx.x;
  const int lane = tid & 63;
  const int w = tid >> 6;
  const int sr = lane & 15;
  const int g = lane >> 4;

  const int q0 = blockIdx.x * 64;
  const int b = blockIdx.y >> 4;
  const int h = blockIdx.y & 15;

  const int usemask = *maskflag;

  const unsigned short* Qb = Q + b * DM + h * DKH;
  const unsigned short* Kb = K + b * DM + h * DKH;
  const unsigned short* Vb = V + b * DM + h * DKH;
  const int RS = BATCH * DM;  // 2048 elem row stride

  // Q fragments for this wave's 16 rows (A-operand: m=lane%16, k=(lane/16)*8+j)
  const int qrow = q0 + w * 16 + sr;
  const short8 aq0 = *(const short8*)&Qb[(size_t)qrow * RS + 0 + g * 8];
  const short8 aq1 = *(const short8*)&Qb[(size_t)qrow * RS + 32 + g * 8];

  f32x4 acc_o[4] = {};
  float mrow[4], lrow[4];
#pragma unroll
  for (int r = 0; r < 4; ++r) { mrow[r] = -3.0e38f; lrow[r] = 0.f; }

  const float SCL = 0.125f;                      // 1/sqrt(64)
  const float L2E = 1.44269504088896340736f;

  const int td = tid & 63;        // transpose: this thread's d column
  const int tt = (tid >> 6) * 16; // and t range [tt, tt+16)

  for (int t0 = 0; t0 < SEQ; t0 += 64) {
    // ---- stage: K swizzled via pre-swizzled global source; V linear
#pragma unroll
    for (int it = 0; it < 2; ++it) {
      const int flat = it * 4096 + tid * 16;           // byte in 8KB tile
      const int tr = flat >> 7;                        // row 0..63
      const int cb = (flat & 127) ^ ((tr & 7) << 4);   // swizzled col byte
      async16(Kb + (size_t)(t0 + tr) * RS + (cb >> 1), (char*)Kl + it * 4096 + w * 1024);
      async16(Vb + (size_t)(t0 + tr) * RS + ((flat & 127) >> 1), (char*)Vlin + it * 4096 + w * 1024);
    }
    __syncthreads();  // staging complete (barrier drains vmcnt)

    // ---- transpose V: Vlin[t][d] -> Vt[d][t]   (reads 2-way conflict = free)
#pragma unroll
    for (int halfi = 0; halfi < 2; ++halfi) {
      const int tb = tt + halfi * 8;
      short8 tmp;
#pragma unroll
      for (int j = 0; j < 8; ++j)
        tmp[j] = (short)Vlin[(tb + j) * 64 + td];
      *(short8*)&Vt[td * 72 + tb] = tmp;
    }

    // ---- QK^T: S[q,t] tile, B-operand = K rows (n = lane%16)
    f32x4 sc[4] = {};
#pragma unroll
    for (int nt = 0; nt < 4; ++nt) {
      const char* kbase = (const char*)Kl + (nt * 16 + sr) * 128;
      const int sw = (sr & 7) << 4;
      short8 b0 = *(const short8*)(kbase + ((0 + g * 16) ^ sw));
      short8 b1 = *(const short8*)(kbase + ((64 + g * 16) ^ sw));
      sc[nt] = __builtin_amdgcn_mfma_f32_16x16x32_bf16(aq0, b0, sc[nt], 0, 0, 0);
      sc[nt] = __builtin_amdgcn_mfma_f32_16x16x32_bf16(aq1, b1, sc[nt], 0, 0, 0);
    }

    // ---- online softmax (fp32). Row r_loc = g*4+r, col = nt*16+sr.
    float pvv[4][4];
#pragma unroll
    for (int nt = 0; nt < 4; ++nt)
#pragma unroll
      for (int r = 0; r < 4; ++r) {
        float vv = sc[nt][r] * SCL;
        if (usemask)
          vv += mask[(size_t)(q0 + w * 16 + g * 4 + r) * SEQ + t0 + nt * 16 + sr];
        pvv[nt][r] = vv;
      }
    float pm[4];
#pragma unroll
    for (int r = 0; r < 4; ++r)
      pm[r] = fmaxf(fmaxf(pvv[0][r], pvv[1][r]), fmaxf(pvv[2][r], pvv[3][r]));
#pragma unroll
    for (int off = 1; off < 16; off <<= 1)
#pragma unroll
      for (int r = 0; r < 4; ++r)
        pm[r] = fmaxf(pm[r], __shfl_xor(pm[r], off));
    float sf[4];
#pragma unroll
    for (int r = 0; r < 4; ++r) {
      const float mn = fmaxf(mrow[r], pm[r]);
      sf[r] = exp2f((mrow[r] - mn) * L2E);
      mrow[r] = mn;
    }
    float rs[4] = {0.f, 0.f, 0.f, 0.f};
#pragma unroll
    for (int nt = 0; nt < 4; ++nt)
#pragma unroll
      for (int r = 0; r < 4; ++r) {
        const float p = exp2f((pvv[nt][r] - mrow[r]) * L2E);
        pvv[nt][r] = p;
        rs[r] += p;
      }
#pragma unroll
    for (int off = 1; off < 16; off <<= 1)
#pragma unroll
      for (int r = 0; r < 4; ++r)
        rs[r] += __shfl_xor(rs[r], off);
#pragma unroll
    for (int r = 0; r < 4; ++r)
      lrow[r] = lrow[r] * sf[r] + rs[r];
#pragma unroll
    for (int nt = 0; nt < 4; ++nt)
#pragma unroll
      for (int r = 0; r < 4; ++r)
        acc_o[nt][r] *= sf[r];

    // ---- P (bf16) to LDS in A-operand-readable layout
#pragma unroll
    for (int nt = 0; nt < 4; ++nt)
#pragma unroll
      for (int r = 0; r < 4; ++r)
        Pl[w][(g * 4 + r) * 72 + nt * 16 + sr] = f2bf(pvv[nt][r]);

    __syncthreads();  // Vt complete (and orders P writes)

    // ---- PV: O[q,d] += P[q,t] @ V[t,d]
#pragma unroll
    for (int kk = 0; kk < 2; ++kk) {
      const short8 pa = *(const short8*)&Pl[w][sr * 72 + kk * 32 + g * 8];
#pragma unroll
      for (int nt = 0; nt < 4; ++nt) {
        const short8 vbf = *(const short8*)&Vt[(nt * 16 + sr) * 72 + kk * 32 + g * 8];
        acc_o[nt] = __builtin_amdgcn_mfma_f32_16x16x32_bf16(pa, vbf, acc_o[nt], 0, 0, 0);
      }
    }
  }

  // epilogue: normalize & write (S,B,D) bf16
  float inv[4];
#pragma unroll
  for (int r = 0; r < 4; ++r) inv[r] = 1.0f / lrow[r];
#pragma unroll
  for (int nt = 0; nt < 4; ++nt)
#pragma unroll
    for (int r = 0; r < 4; ++r)
      O[(size_t)(q0 + w * 16 + g * 4 + r) * RS + b * DM + h * DKH + nt * 16 + sr] =
          f2bf(acc_o[nt][r] * inv[r]);
}

// ---------------------------------------------------------------------------
// Launch
// ---------------------------------------------------------------------------
extern "C" void kernel_launch(void* const* d_in, const int* in_sizes, int n_in,
                              void* d_out, int out_size, void* d_ws, size_t ws_size,
                              hipStream_t stream) {
  const float* q = (const float*)d_in[0];
  const float* k = (const float*)d_in[1];
  const float* v = (const float*)d_in[2];
  const float* msk = (const float*)d_in[3];
  const float* Wq = (const float*)d_in[4];
  const float* bq = (const float*)d_in[5];
  const float* Wk = (const float*)d_in[6];
  const float* bk = (const float*)d_in[7];
  const float* Wv = (const float*)d_in[8];
  const float* bv = (const float*)d_in[9];
  const float* Wo = (const float*)d_in[10];
  const float* bo = (const float*)d_in[11];
  float* out = (float*)d_out;

  char* ws = (char*)d_ws;
  const size_t SZX = (size_t)MROWS * DM * 2;   // 8 MB bf16 activation
  const size_t SZW = (size_t)DM * DM * 2;      // 2 MB bf16 weight
  unsigned short* qb  = (unsigned short*)(ws + 0 * SZX);
  unsigned short* kb  = (unsigned short*)(ws + 1 * SZX);
  unsigned short* vb  = (unsigned short*)(ws + 2 * SZX);
  unsigned short* Wqb = (unsigned short*)(ws + 3 * SZX + 0 * SZW);
  unsigned short* Wkb = (unsigned short*)(ws + 3 * SZX + 1 * SZW);
  unsigned short* Wvb = (unsigned short*)(ws + 3 * SZX + 2 * SZW);
  unsigned short* Wob = (unsigned short*)(ws + 3 * SZX + 3 * SZW);
  unsigned short* Qh  = (unsigned short*)(ws + 3 * SZX + 4 * SZW + 0 * SZX);
  unsigned short* Kh  = (unsigned short*)(ws + 3 * SZX + 4 * SZW + 1 * SZX);
  unsigned short* Vh  = (unsigned short*)(ws + 3 * SZX + 4 * SZW + 2 * SZX);
  unsigned short* AO  = (unsigned short*)(ws + 3 * SZX + 4 * SZW + 3 * SZX);
  int* flag = (int*)(ws + 7 * SZX + 4 * SZW);

  hipMemsetAsync(flag, 0, 4, stream);

  CvtArgs ca;
  ca.s[0] = q;  ca.d[0] = qb;  ca.n[0] = MROWS * DM;
  ca.s[1] = k;  ca.d[1] = kb;  ca.n[1] = MROWS * DM;
  ca.s[2] = v;  ca.d[2] = vb;  ca.n[2] = MROWS * DM;
  ca.s[3] = Wq; ca.d[3] = Wqb; ca.n[3] = DM * DM;
  ca.s[4] = Wk; ca.d[4] = Wkb; ca.n[4] = DM * DM;
  ca.s[5] = Wv; ca.d[5] = Wvb; ca.n[5] = DM * DM;
  ca.s[6] = Wo; ca.d[6] = Wob; ca.n[6] = DM * DM;
  ca.s[7] = q;  ca.d[7] = qb;  ca.n[7] = 0;
  cvt_kernel<<<dim3(4096, 7, 1), 256, 0, stream>>>(ca);

  maskchk_kernel<<<dim3(2048, 1, 1), 256, 0, stream>>>(msk, SEQ * SEQ, flag);

  GemmPtrs gp;
  gp.A[0] = qb; gp.W[0] = Wqb; gp.bias[0] = bq; gp.C[0] = Qh;
  gp.A[1] = kb; gp.W[1] = Wkb; gp.bias[1] = bk; gp.C[1] = Kh;
  gp.A[2] = vb; gp.W[2] = Wvb; gp.bias[2] = bv; gp.C[2] = Vh;
  gemm_qkv_kernel<<<dim3(32, 8, 3), 256, 0, stream>>>(gp, MROWS, DM, DM);

  attn_kernel<<<dim3(32, 32, 1), 256, 0, stream>>>(Qh, Kh, Vh, msk, flag, AO);

  gemm_f32_kernel<<<dim3(32, 8, 1), 256, 0, stream>>>(AO, Wob, bo, out, MROWS, DM, DM);
}

// Round 2
// 188.271 us; speedup vs baseline: 1.2531x; 1.2531x over previous
//
#include <hip/hip_runtime.h>

// ---------------------------------------------------------------------------
// MultiHeadAttention forward, MI355X/gfx950.
// cvt(fp32->bf16) -> QKV proj (bf16 MFMA) -> V transpose -> flash attn
// (swapped-QK in-lane softmax, double-buffered staging) -> out proj.
// ---------------------------------------------------------------------------

#define DEV static __device__ __forceinline__

typedef unsigned short u16;
typedef __attribute__((ext_vector_type(8))) short short8;
typedef __attribute__((ext_vector_type(4))) float f32x4;
typedef __attribute__((ext_vector_type(4))) unsigned short ushort4v;

#define SEQ   2048
#define BATCH 2
#define DM    1024
#define NH    16
#define DKH   64
#define MROWS (SEQ*BATCH)   // 4096

DEV u16 f2bf(float f) {
  union { float f; unsigned int u; } v; v.f = f;
  unsigned int u = v.u;
  return (u16)((u + 0x7FFFu + ((u >> 16) & 1u)) >> 16);  // RNE
}

// async global->LDS, 16B per lane. LDS dest is wave-uniform base + lane*16.
DEV void async16(const void* g, void* l) {
  __builtin_amdgcn_global_load_lds(
      (const __attribute__((address_space(1))) unsigned int*)g,
      (__attribute__((address_space(3))) unsigned int*)l, 16, 0, 0);
}

// ---------------------------------------------------------------------------
// fp32 -> bf16 conversion, 7 tensors in one launch (grid.y = tensor id)
// ---------------------------------------------------------------------------
struct CvtArgs {
  const float* s[8];
  u16* d[8];
  int n[8];
};

__global__ __launch_bounds__(256) void cvt_kernel(CvtArgs a) {
  const int t = blockIdx.y;
  const float* __restrict__ s = a.s[t];
  u16* __restrict__ d = a.d[t];
  const int n = a.n[t];
  const int i = (blockIdx.x * 256 + threadIdx.x) * 4;
  if (i >= n) return;
  f32x4 f = *(const f32x4*)&s[i];
  ushort4v o;
  o[0] = f2bf(f[0]); o[1] = f2bf(f[1]); o[2] = f2bf(f[2]); o[3] = f2bf(f[3]);
  *(ushort4v*)&d[i] = o;
}

// mask-nonzero detector (mask is all zeros here; keep general for correctness)
__global__ __launch_bounds__(256) void maskchk_kernel(const float* __restrict__ m, int n, int* flag) {
  int any = 0;
  const int stride = gridDim.x * 256 * 4;
  for (int i = (blockIdx.x * 256 + threadIdx.x) * 4; i < n; i += stride) {
    f32x4 v = *(const f32x4*)&m[i];
    any |= (v[0] != 0.f);
    any |= (v[1] != 0.f);
    any |= (v[2] != 0.f);
    any |= (v[3] != 0.f);
  }
  if (any) atomicOr(flag, 1);
}

// ---------------------------------------------------------------------------
// GEMM: C[M,N] = A[M,K] @ W[N,K]^T + bias.  128x128 tile, BK=64, 4 waves.
// ---------------------------------------------------------------------------
template <typename OutT>
DEV void gemm_body(const u16* __restrict__ A,
                   const u16* __restrict__ W,
                   const float* __restrict__ bias,
                   OutT* __restrict__ C,
                   u16* As, u16* Bs,
                   int M, int N, int K, int m0, int n0) {
  const int tid = threadIdx.x;
  const int lane = tid & 63;
  const int wid = tid >> 6;
  const int wr = wid >> 1, wc = wid & 1;   // 2x2 wave grid, 64x64 per wave
  const int sr = lane & 15, g = lane >> 4;

  f32x4 acc[4][4] = {};

  const int arow = tid >> 3;          // 0..31
  const int acol = (tid & 7) * 8;     // elem col within 64
  const size_t abase = (size_t)(m0 + arow) * K + acol;
  const size_t bbase = (size_t)(n0 + arow) * K + acol;

  for (int kt = 0; kt < K; kt += 64) {
#pragma unroll
    for (int j = 0; j < 4; ++j) {
      async16(A + abase + (size_t)j * 32 * K + kt, (char*)As + j * 4096 + wid * 1024);
      async16(W + bbase + (size_t)j * 32 * K + kt, (char*)Bs + j * 4096 + wid * 1024);
    }
    __syncthreads();
#pragma unroll
    for (int kk = 0; kk < 2; ++kk) {
      short8 af[4], bf[4];
#pragma unroll
      for (int mt = 0; mt < 4; ++mt)
        af[mt] = *(const short8*)&As[(wr * 64 + mt * 16 + sr) * 64 + kk * 32 + g * 8];
#pragma unroll
      for (int nt = 0; nt < 4; ++nt)
        bf[nt] = *(const short8*)&Bs[(wc * 64 + nt * 16 + sr) * 64 + kk * 32 + g * 8];
#pragma unroll
      for (int mt = 0; mt < 4; ++mt)
#pragma unroll
        for (int nt = 0; nt < 4; ++nt)
          acc[mt][nt] = __builtin_amdgcn_mfma_f32_16x16x32_bf16(af[mt], bf[nt], acc[mt][nt], 0, 0, 0);
    }
    __syncthreads();
  }

  // C/D layout: row=(lane>>4)*4+reg, col=lane&15  [m89-verified]
#pragma unroll
  for (int nt = 0; nt < 4; ++nt) {
    const int col = n0 + wc * 64 + nt * 16 + sr;
    const float bv = bias[col];
#pragma unroll
    for (int mt = 0; mt < 4; ++mt) {
#pragma unroll
      for (int r = 0; r < 4; ++r) {
        const int row = m0 + wr * 64 + mt * 16 + g * 4 + r;
        const float val = acc[mt][nt][r] + bv;
        if constexpr (sizeof(OutT) == 2)
          C[(size_t)row * N + col] = f2bf(val);
        else
          C[(size_t)row * N + col] = val;
      }
    }
  }
}

struct GemmPtrs {
  const u16* A[3];
  const u16* W[3];
  const float* bias[3];
  u16* C[3];
};

__global__ __launch_bounds__(256) void gemm_qkv_kernel(GemmPtrs p, int M, int N, int K) {
  __shared__ u16 As[128 * 64];
  __shared__ u16 Bs[128 * 64];
  const int z = blockIdx.z;
  gemm_body<u16>(p.A[z], p.W[z], p.bias[z], p.C[z], As, Bs,
                 M, N, K, blockIdx.x * 128, blockIdx.y * 128);
}

__global__ __launch_bounds__(256) void gemm_f32_kernel(const u16* __restrict__ A,
                                                       const u16* __restrict__ W,
                                                       const float* __restrict__ bias,
                                                       float* __restrict__ C,
                                                       int M, int N, int K) {
  __shared__ u16 As[128 * 64];
  __shared__ u16 Bs[128 * 64];
  gemm_body<float>(A, W, bias, C, As, Bs, M, N, K, blockIdx.x * 128, blockIdx.y * 128);
}

// ---------------------------------------------------------------------------
// V transpose: Vh (S,B,D) bf16 -> VT[bh][dk][t]  (shape [32][64][2048])
// One (64t x 64dk) tile per block.
// ---------------------------------------------------------------------------
__global__ __launch_bounds__(256) void vtrans_kernel(const u16* __restrict__ Vh,
                                                     u16* __restrict__ VT) {
  __shared__ u16 tl[4096];   // [t][dk] linear
  const int tid = threadIdx.x;
  const int w = tid >> 6;
  const int t0 = blockIdx.x * 64;
  const int bh = blockIdx.y;
  const int b = bh >> 4, h = bh & 15;
  const int str = tid >> 3;          // t row 0..31
  const int scc = (tid & 7) * 8;     // dk col (elems)
#pragma unroll
  for (int it = 0; it < 2; ++it)
    async16(Vh + (size_t)((t0 + str + it * 32) * 2 + b) * 1024 + h * 64 + scc,
            (char*)tl + it * 4096 + w * 1024);
  __syncthreads();
  const int dk = tid >> 2;
  const int t4 = (tid & 3) * 16;
  short8 ov[2];
#pragma unroll
  for (int half = 0; half < 2; ++half)
#pragma unroll
    for (int j = 0; j < 8; ++j)
      ov[half][j] = (short)tl[(t4 + half * 8 + j) * 64 + dk];
  u16* dst = VT + (size_t)(bh * 64 + dk) * 2048 + t0 + t4;
  *(short8*)dst = ov[0];
  *(short8*)(dst + 8) = ov[1];
}

// ---------------------------------------------------------------------------
// Flash attention v2.  Grid (SEQ/128, B*H), 256 thr = 4 waves.
// Wave owns 32 q-rows (2 sets of 16).  KV tile 64.
// Swapped QK^T: S^T = mfma(A=K, B=Q) -> lane holds P[t...][q=sr] -> in-lane
// softmax + 2 shfl_xor.  K and VT staged via global_load_lds with both-sides
// XOR swizzle (rule #21).  P per-wave in LDS, stride 72 (bank-balanced).
// 2-phase double-buffer: stage(t+1) issued before compute(t), 1 barrier/tile.
// ---------------------------------------------------------------------------
__global__ __launch_bounds__(256, 2) void attn2_kernel(const u16* __restrict__ Q,
                                                       const u16* __restrict__ K,
                                                       const u16* __restrict__ VT,
                                                       const float* __restrict__ mask,
                                                       const int* __restrict__ maskflag,
                                                       u16* __restrict__ O) {
  __shared__ u16 Kl[2][4096];
  __shared__ u16 Vl[2][4096];
  __shared__ u16 Pl[4][32 * 72];

  const int tid = threadIdx.x;
  const int lane = tid & 63;
  const int w = tid >> 6;
  const int sr = lane & 15;
  const int g = lane >> 4;
  const int sw = (sr & 7) << 4;

  const int q0 = blockIdx.x * 128 + w * 32;
  const int bh = blockIdx.y;
  const int b = bh >> 4, h = bh & 15;
  const int usemask = *maskflag;

  const u16* Qb = Q + b * DM + h * DKH;
  const u16* Kb = K + b * DM + h * DKH;
  const u16* VTb = VT + (size_t)bh * 64 * 2048;

  // Q fragments (B-operand: lane holds q-row n=sr, k=g*8+j)
  short8 aq[2][2];
#pragma unroll
  for (int s = 0; s < 2; ++s)
#pragma unroll
    for (int kk = 0; kk < 2; ++kk)
      aq[s][kk] = *(const short8*)&Qb[(size_t)(q0 + s * 16 + sr) * 2048 + kk * 32 + g * 8];

  f32x4 acc[2][4] = {};
  float m_[2] = {-1e30f, -1e30f};
  float l_[2] = {0.f, 0.f};

  const int strow = tid >> 3;                                  // staged row 0..31
  const int scb = (((tid & 7) * 16) ^ ((strow & 7) << 4)) >> 1; // pre-swizzled col (elems)

  auto STAGE = [&](int nb, int t0n) {
#pragma unroll
    for (int it = 0; it < 2; ++it) {
      async16(Kb + (size_t)(t0n + strow + it * 32) * 2048 + scb,
              (char*)&Kl[nb][0] + it * 4096 + w * 1024);
      async16(VTb + (size_t)(strow + it * 32) * 2048 + t0n + scb,
              (char*)&Vl[nb][0] + it * 4096 + w * 1024);
    }
  };

  STAGE(0, 0);
  __syncthreads();
  int cur = 0;
  const float SCL = 0.125f;             // 1/sqrt(64)
  const float L2E = 1.44269504088896f;

  for (int t0 = 0; t0 < SEQ; t0 += 64) {
    if (t0 + 64 < SEQ) STAGE(cur ^ 1, t0 + 64);

    // K fragments (A-operand: row t=16nt+sr, k=kk*32+g*8), swizzled read
    short8 kf[4][2];
#pragma unroll
    for (int nt = 0; nt < 4; ++nt)
#pragma unroll
      for (int kk = 0; kk < 2; ++kk)
        kf[nt][kk] = *(const short8*)((const char*)&Kl[cur][0] +
                                      (nt * 16 + sr) * 128 + ((kk * 64 + g * 16) ^ sw));

    // S^T[t][q] = K . Q^T : lane holds q=sr, t = 16nt + 4g + r
    f32x4 sc[2][4] = {};
#pragma unroll
    for (int s = 0; s < 2; ++s)
#pragma unroll
      for (int nt = 0; nt < 4; ++nt)
#pragma unroll
        for (int kk = 0; kk < 2; ++kk)
          sc[s][nt] = __builtin_amdgcn_mfma_f32_16x16x32_bf16(kf[nt][kk], aq[s][kk], sc[s][nt], 0, 0, 0);

#pragma unroll
    for (int s = 0; s < 2; ++s) {
      float x[4][4];
#pragma unroll
      for (int nt = 0; nt < 4; ++nt)
#pragma unroll
        for (int r = 0; r < 4; ++r)
          x[nt][r] = sc[s][nt][r] * SCL;
      if (usemask) {
        const int qg = q0 + s * 16 + sr;
#pragma unroll
        for (int nt = 0; nt < 4; ++nt)
#pragma unroll
          for (int r = 0; r < 4; ++r)
            x[nt][r] += mask[(size_t)qg * SEQ + t0 + nt * 16 + g * 4 + r];
      }
      // row max: in-lane 16 + cross-g butterfly
      float pm = x[0][0];
#pragma unroll
      for (int nt = 0; nt < 4; ++nt)
#pragma unroll
        for (int r = 0; r < 4; ++r)
          pm = fmaxf(pm, x[nt][r]);
      pm = fmaxf(pm, __shfl_xor(pm, 16));
      pm = fmaxf(pm, __shfl_xor(pm, 32));
      // T13 defer-rescale (THR=8 -> P bounded by 2^11.5, fine in bf16/f32)
      if (__any(pm - m_[s] > 8.f)) {
        const float mn = fmaxf(m_[s], pm);
        const float sf = exp2f((m_[s] - mn) * L2E);
        m_[s] = mn;
        l_[s] *= sf;
        float sfb[4];
#pragma unroll
        for (int r = 0; r < 4; ++r) sfb[r] = __shfl(sf, g * 4 + r);
#pragma unroll
        for (int nd = 0; nd < 4; ++nd)
#pragma unroll
          for (int r = 0; r < 4; ++r) acc[s][nd][r] *= sfb[r];
      }
      const float mm = m_[s] * L2E;
      float rs = 0.f;
#pragma unroll
      for (int nt = 0; nt < 4; ++nt) {
        ushort4v pw;
#pragma unroll
        for (int r = 0; r < 4; ++r) {
          const float p = exp2f(__builtin_fmaf(x[nt][r], L2E, -mm));
          rs += p;
          pw[r] = f2bf(p);
        }
        // P row = s*16+sr, t chunk [16nt+4g, +4), b64 write
        *(ushort4v*)&Pl[w][(s * 16 + sr) * 72 + nt * 16 + g * 4] = pw;
      }
      rs += __shfl_xor(rs, 16);
      rs += __shfl_xor(rs, 32);
      l_[s] += rs;
    }

    // V^T fragments (B-operand: row d=16nd+sr, k=t=kk*32+g*8), swizzled
    short8 vf[4][2];
#pragma unroll
    for (int nd = 0; nd < 4; ++nd)
#pragma unroll
      for (int kk = 0; kk < 2; ++kk)
        vf[nd][kk] = *(const short8*)((const char*)&Vl[cur][0] +
                                      (nd * 16 + sr) * 128 + ((kk * 64 + g * 16) ^ sw));

    // O[q][d] += P[q][t] V[t][d]
#pragma unroll
    for (int s = 0; s < 2; ++s) {
      short8 pf[2];
#pragma unroll
      for (int kk = 0; kk < 2; ++kk)
        pf[kk] = *(const short8*)&Pl[w][(s * 16 + sr) * 72 + kk * 32 + g * 8];
#pragma unroll
      for (int kk = 0; kk < 2; ++kk)
#pragma unroll
        for (int nd = 0; nd < 4; ++nd)
          acc[s][nd] = __builtin_amdgcn_mfma_f32_16x16x32_bf16(pf[kk], vf[nd][kk], acc[s][nd], 0, 0, 0);
    }
    __syncthreads();   // waves done with buf[cur]; prefetch of buf[cur^1] drained
    cur ^= 1;
  }

  // epilogue: O rows are q_loc=g*4+r but l_ lives at lane sr=q_loc -> broadcast
#pragma unroll
  for (int s = 0; s < 2; ++s) {
    const float linv = 1.f / l_[s];
    float lb[4];
#pragma unroll
    for (int r = 0; r < 4; ++r) lb[r] = __shfl(linv, g * 4 + r);
#pragma unroll
    for (int nd = 0; nd < 4; ++nd)
#pragma unroll
      for (int r = 0; r < 4; ++r) {
        const int q = q0 + s * 16 + g * 4 + r;
        O[(size_t)q * 2048 + b * DM + h * DKH + nd * 16 + sr] = f2bf(acc[s][nd][r] * lb[r]);
      }
  }
}

// ---------------------------------------------------------------------------
// Launch
// ---------------------------------------------------------------------------
extern "C" void kernel_launch(void* const* d_in, const int* in_sizes, int n_in,
                              void* d_out, int out_size, void* d_ws, size_t ws_size,
                              hipStream_t stream) {
  const float* q = (const float*)d_in[0];
  const float* k = (const float*)d_in[1];
  const float* v = (const float*)d_in[2];
  const float* msk = (const float*)d_in[3];
  const float* Wq = (const float*)d_in[4];
  const float* bq = (const float*)d_in[5];
  const float* Wk = (const float*)d_in[6];
  const float* bk = (const float*)d_in[7];
  const float* Wv = (const float*)d_in[8];
  const float* bv = (const float*)d_in[9];
  const float* Wo = (const float*)d_in[10];
  const float* bo = (const float*)d_in[11];
  float* out = (float*)d_out;

  char* ws = (char*)d_ws;
  const size_t SZX = (size_t)MROWS * DM * 2;   // 8 MB bf16 activation
  const size_t SZW = (size_t)DM * DM * 2;      // 2 MB bf16 weight
  u16* qb  = (u16*)(ws + 0 * SZX);
  u16* kb  = (u16*)(ws + 1 * SZX);
  u16* vb  = (u16*)(ws + 2 * SZX);
  u16* Wqb = (u16*)(ws + 3 * SZX + 0 * SZW);
  u16* Wkb = (u16*)(ws + 3 * SZX + 1 * SZW);
  u16* Wvb = (u16*)(ws + 3 * SZX + 2 * SZW);
  u16* Wob = (u16*)(ws + 3 * SZX + 3 * SZW);
  u16* Qh  = (u16*)(ws + 3 * SZX + 4 * SZW + 0 * SZX);
  u16* Kh  = (u16*)(ws + 3 * SZX + 4 * SZW + 1 * SZX);
  u16* Vh  = (u16*)(ws + 3 * SZX + 4 * SZW + 2 * SZX);
  u16* AO  = (u16*)(ws + 3 * SZX + 4 * SZW + 3 * SZX);
  int* flag = (int*)(ws + 7 * SZX + 4 * SZW);
  // VT reuses qb's region (qb is dead after gemm_qkv): [32 bh][64 dk][2048 t] = 8 MB
  u16* VTg = qb;

  hipMemsetAsync(flag, 0, 4, stream);

  CvtArgs ca;
  ca.s[0] = q;  ca.d[0] = qb;  ca.n[0] = MROWS * DM;
  ca.s[1] = k;  ca.d[1] = kb;  ca.n[1] = MROWS * DM;
  ca.s[2] = v;  ca.d[2] = vb;  ca.n[2] = MROWS * DM;
  ca.s[3] = Wq; ca.d[3] = Wqb; ca.n[3] = DM * DM;
  ca.s[4] = Wk; ca.d[4] = Wkb; ca.n[4] = DM * DM;
  ca.s[5] = Wv; ca.d[5] = Wvb; ca.n[5] = DM * DM;
  ca.s[6] = Wo; ca.d[6] = Wob; ca.n[6] = DM * DM;
  ca.s[7] = q;  ca.d[7] = qb;  ca.n[7] = 0;
  cvt_kernel<<<dim3(4096, 7, 1), 256, 0, stream>>>(ca);

  maskchk_kernel<<<dim3(2048, 1, 1), 256, 0, stream>>>(msk, SEQ * SEQ, flag);

  GemmPtrs gp;
  gp.A[0] = qb; gp.W[0] = Wqb; gp.bias[0] = bq; gp.C[0] = Qh;
  gp.A[1] = kb; gp.W[1] = Wkb; gp.bias[1] = bk; gp.C[1] = Kh;
  gp.A[2] = vb; gp.W[2] = Wvb; gp.bias[2] = bv; gp.C[2] = Vh;
  gemm_qkv_kernel<<<dim3(32, 8, 3), 256, 0, stream>>>(gp, MROWS, DM, DM);

  vtrans_kernel<<<dim3(32, 32, 1), 256, 0, stream>>>(Vh, VTg);

  attn2_kernel<<<dim3(16, 32, 1), 256, 0, stream>>>(Qh, Kh, VTg, msk, flag, AO);

  gemm_f32_kernel<<<dim3(32, 8, 1), 256, 0, stream>>>(AO, Wob, bo, out, MROWS, DM, DM);
}

// Round 3
// 178.083 us; speedup vs baseline: 1.3248x; 1.0572x over previous
//
#include <hip/hip_runtime.h>

// ---------------------------------------------------------------------------
// MultiHeadAttention forward, MI355X/gfx950.
// cvt(fp32->bf16, Wq pre-scaled by 1/8) + mask-check -> QKV proj (bf16 MFMA)
// -> V transpose -> flash attn (swapped-QK in-lane softmax, dbuf staging,
// XCD-swizzled grid, setprio) -> out proj (64x128 tiles, 2 blocks/CU).
// ---------------------------------------------------------------------------

#define DEV static __device__ __forceinline__

typedef unsigned short u16;
typedef __attribute__((ext_vector_type(8))) short short8;
typedef __attribute__((ext_vector_type(4))) float f32x4;
typedef __attribute__((ext_vector_type(4))) unsigned short ushort4v;

#define SEQ   2048
#define BATCH 2
#define DM    1024
#define NH    16
#define DKH   64
#define MROWS (SEQ*BATCH)   // 4096

DEV u16 f2bf(float f) {            // RNE
  union { float f; unsigned int u; } v; v.f = f;
  unsigned int u = v.u;
  return (u16)((u + 0x7FFFu + ((u >> 16) & 1u)) >> 16);
}
DEV u16 f2bf_h(float f) {          // round-half-up: 2 VALU ops (P values only)
  union { float f; unsigned int u; } v; v.f = f;
  return (u16)((v.u + 0x8000u) >> 16);
}
DEV float max3f(float a, float b, float c) { return fmaxf(fmaxf(a, b), c); }

// async global->LDS, 16B per lane. LDS dest is wave-uniform base + lane*16.
DEV void async16(const void* g, void* l) {
  __builtin_amdgcn_global_load_lds(
      (const __attribute__((address_space(1))) unsigned int*)g,
      (__attribute__((address_space(3))) unsigned int*)l, 16, 0, 0);
}

// ---------------------------------------------------------------------------
// fp32 -> bf16 conversion (grid.y = tensor id; y==7 is the mask-zero scan)
// ---------------------------------------------------------------------------
struct CvtArgs {
  const float* s[8];
  u16* d[8];
  int n[8];
  float scale[8];
  int* flag;
};

__global__ __launch_bounds__(256) void cvt_kernel(CvtArgs a) {
  const int t = blockIdx.y;
  const int n = a.n[t];
  const int stride = 1024 * 256 * 4;
  if (t == 7) {   // mask scan
    const float* __restrict__ m = a.s[7];
    int any = 0;
    for (int i = (blockIdx.x * 256 + threadIdx.x) * 4; i < n; i += stride) {
      f32x4 v = *(const f32x4*)&m[i];
      any |= (v[0] != 0.f); any |= (v[1] != 0.f);
      any |= (v[2] != 0.f); any |= (v[3] != 0.f);
    }
    if (any) atomicOr(a.flag, 1);
    return;
  }
  const float* __restrict__ s = a.s[t];
  u16* __restrict__ d = a.d[t];
  const float sc = a.scale[t];
  for (int i = (blockIdx.x * 256 + threadIdx.x) * 4; i < n; i += stride) {
    f32x4 f = *(const f32x4*)&s[i];
    ushort4v o;
    o[0] = f2bf(f[0] * sc); o[1] = f2bf(f[1] * sc);
    o[2] = f2bf(f[2] * sc); o[3] = f2bf(f[3] * sc);
    *(ushort4v*)&d[i] = o;
  }
}

// ---------------------------------------------------------------------------
// GEMM: C[M,N] = A[M,K] @ W[N,K]^T + bias*bscale.
// Block tile (MT*32) x (NT*32), BK=64, 4 waves in 2x2.
// ---------------------------------------------------------------------------
template <int MT, int NT, typename OutT>
DEV void gemm_body(const u16* __restrict__ A,
                   const u16* __restrict__ W,
                   const float* __restrict__ bias, float bscale,
                   OutT* __restrict__ C,
                   u16* As, u16* Bs,
                   int M, int N, int K, int m0, int n0) {
  const int tid = threadIdx.x;
  const int lane = tid & 63;
  const int wid = tid >> 6;
  const int wr = wid >> 1, wc = wid & 1;
  const int sr = lane & 15, g = lane >> 4;

  f32x4 acc[MT][NT] = {};

  const int arow = tid >> 3;          // 0..31
  const int acol = (tid & 7) * 8;     // elem col within 64
  const size_t abase = (size_t)(m0 + arow) * K + acol;
  const size_t bbase = (size_t)(n0 + arow) * K + acol;

  for (int kt = 0; kt < K; kt += 64) {
#pragma unroll
    for (int j = 0; j < MT; ++j)
      async16(A + abase + (size_t)j * 32 * K + kt, (char*)As + j * 4096 + wid * 1024);
#pragma unroll
    for (int j = 0; j < NT; ++j)
      async16(W + bbase + (size_t)j * 32 * K + kt, (char*)Bs + j * 4096 + wid * 1024);
    __syncthreads();
#pragma unroll
    for (int kk = 0; kk < 2; ++kk) {
      short8 af[MT], bf[NT];
#pragma unroll
      for (int mt = 0; mt < MT; ++mt)
        af[mt] = *(const short8*)&As[(wr * MT * 16 + mt * 16 + sr) * 64 + kk * 32 + g * 8];
#pragma unroll
      for (int nt = 0; nt < NT; ++nt)
        bf[nt] = *(const short8*)&Bs[(wc * NT * 16 + nt * 16 + sr) * 64 + kk * 32 + g * 8];
#pragma unroll
      for (int mt = 0; mt < MT; ++mt)
#pragma unroll
        for (int nt = 0; nt < NT; ++nt)
          acc[mt][nt] = __builtin_amdgcn_mfma_f32_16x16x32_bf16(af[mt], bf[nt], acc[mt][nt], 0, 0, 0);
    }
    __syncthreads();
  }

  // C/D layout: row=(lane>>4)*4+reg, col=lane&15  [m89-verified]
#pragma unroll
  for (int nt = 0; nt < NT; ++nt) {
    const int col = n0 + wc * NT * 16 + nt * 16 + sr;
    const float bv = bias[col] * bscale;
#pragma unroll
    for (int mt = 0; mt < MT; ++mt) {
#pragma unroll
      for (int r = 0; r < 4; ++r) {
        const int row = m0 + wr * MT * 16 + mt * 16 + g * 4 + r;
        const float val = acc[mt][nt][r] + bv;
        if constexpr (sizeof(OutT) == 2)
          C[(size_t)row * N + col] = f2bf(val);
        else
          C[(size_t)row * N + col] = val;
      }
    }
  }
}

struct GemmPtrs {
  const u16* A[3];
  const u16* W[3];
  const float* bias[3];
  float bscale[3];
  u16* C[3];
};

__global__ __launch_bounds__(256) void gemm_qkv_kernel(GemmPtrs p, int M, int N, int K) {
  __shared__ u16 As[128 * 64];
  __shared__ u16 Bs[128 * 64];
  const int z = blockIdx.z;
  gemm_body<4, 4, u16>(p.A[z], p.W[z], p.bias[z], p.bscale[z], p.C[z], As, Bs,
                       M, N, K, blockIdx.x * 128, blockIdx.y * 128);
}

__global__ __launch_bounds__(256) void gemm_f32_kernel(const u16* __restrict__ A,
                                                       const u16* __restrict__ W,
                                                       const float* __restrict__ bias,
                                                       float* __restrict__ C,
                                                       int M, int N, int K) {
  __shared__ u16 As[64 * 64];
  __shared__ u16 Bs[128 * 64];
  gemm_body<2, 4, float>(A, W, bias, 1.0f, C, As, Bs, M, N, K,
                         blockIdx.x * 64, blockIdx.y * 128);
}

// ---------------------------------------------------------------------------
// V transpose: Vh (S,B,D) bf16 -> VT[bh][dk][t]  (shape [32][64][2048])
// ---------------------------------------------------------------------------
__global__ __launch_bounds__(256) void vtrans_kernel(const u16* __restrict__ Vh,
                                                     u16* __restrict__ VT) {
  __shared__ u16 tl[4096];   // [t][dk] linear
  const int tid = threadIdx.x;
  const int w = tid >> 6;
  const int t0 = blockIdx.x * 64;
  const int bh = blockIdx.y;
  const int b = bh >> 4, h = bh & 15;
  const int str = tid >> 3;
  const int scc = (tid & 7) * 8;
#pragma unroll
  for (int it = 0; it < 2; ++it)
    async16(Vh + (size_t)((t0 + str + it * 32) * 2 + b) * 1024 + h * 64 + scc,
            (char*)tl + it * 4096 + w * 1024);
  __syncthreads();
  const int dk = tid >> 2;
  const int t4 = (tid & 3) * 16;
  short8 ov[2];
#pragma unroll
  for (int half = 0; half < 2; ++half)
#pragma unroll
    for (int j = 0; j < 8; ++j)
      ov[half][j] = (short)tl[(t4 + half * 8 + j) * 64 + dk];
  u16* dst = VT + (size_t)(bh * 64 + dk) * 2048 + t0 + t4;
  *(short8*)dst = ov[0];
  *(short8*)(dst + 8) = ov[1];
}

// ---------------------------------------------------------------------------
// Flash attention v3.  Flat grid 512, XCD-swizzled (T1).  4 waves, wave owns
// 32 q-rows.  KV tile 64.  Swapped QK^T (scale pre-folded into Wq): lane
// holds P[t...][q=sr] -> in-lane softmax + 2 shfl_xor.  K/VT staged via
// global_load_lds with both-sides XOR swizzle.  setprio around MFMA (T5).
// ---------------------------------------------------------------------------
__global__ __launch_bounds__(256, 2) void attn3_kernel(const u16* __restrict__ Q,
                                                       const u16* __restrict__ K,
                                                       const u16* __restrict__ VT,
                                                       const float* __restrict__ mask,
                                                       const int* __restrict__ maskflag,
                                                       u16* __restrict__ O) {
  __shared__ u16 Kl[2][4096];
  __shared__ u16 Vl[2][4096];
  __shared__ u16 Pl[4][32 * 72];

  const int tid = threadIdx.x;
  const int lane = tid & 63;
  const int w = tid >> 6;
  const int sr = lane & 15;
  const int g = lane >> 4;
  const int sw = (sr & 7) << 4;

  // T1: cluster the 16 q-blocks of each bh on one XCD (512 = 8 XCDs x 64)
  const int flat = blockIdx.x;
  const int virt = ((flat & 7) << 6) | (flat >> 3);
  const int qi = virt & 15;
  const int bh = virt >> 4;
  const int q0 = qi * 128 + w * 32;
  const int b = bh >> 4, h = bh & 15;
  const int usemask = *maskflag;

  const u16* Qb = Q + b * DM + h * DKH;
  const u16* Kb = K + b * DM + h * DKH;
  const u16* VTb = VT + (size_t)bh * 64 * 2048;

  // Q fragments (B-operand: lane holds q-row n=sr, k=g*8+j); Q pre-scaled 1/8
  short8 aq[2][2];
#pragma unroll
  for (int s = 0; s < 2; ++s)
#pragma unroll
    for (int kk = 0; kk < 2; ++kk)
      aq[s][kk] = *(const short8*)&Qb[(size_t)(q0 + s * 16 + sr) * 2048 + kk * 32 + g * 8];

  f32x4 acc[2][4] = {};
  float m_[2] = {-1e30f, -1e30f};
  float l_[2] = {0.f, 0.f};

  const int strow = tid >> 3;
  const int scb = (((tid & 7) * 16) ^ ((strow & 7) << 4)) >> 1;

  auto STAGE = [&](int nb, int t0n) {
#pragma unroll
    for (int it = 0; it < 2; ++it) {
      async16(Kb + (size_t)(t0n + strow + it * 32) * 2048 + scb,
              (char*)&Kl[nb][0] + it * 4096 + w * 1024);
      async16(VTb + (size_t)(strow + it * 32) * 2048 + t0n + scb,
              (char*)&Vl[nb][0] + it * 4096 + w * 1024);
    }
  };

  STAGE(0, 0);
  __syncthreads();
  int cur = 0;
  const float L2E = 1.44269504088896f;

  for (int t0 = 0; t0 < SEQ; t0 += 64) {
    if (t0 + 64 < SEQ) STAGE(cur ^ 1, t0 + 64);

    // K fragments (A-operand: row t=16nt+sr, k=kk*32+g*8), swizzled read
    short8 kf[4][2];
#pragma unroll
    for (int nt = 0; nt < 4; ++nt)
#pragma unroll
      for (int kk = 0; kk < 2; ++kk)
        kf[nt][kk] = *(const short8*)((const char*)&Kl[cur][0] +
                                      (nt * 16 + sr) * 128 + ((kk * 64 + g * 16) ^ sw));

    // S^T[t][q] = K . Q^T : lane holds q=sr, t = 16nt + 4g + r
    f32x4 sc[2][4] = {};
    __builtin_amdgcn_s_setprio(1);
#pragma unroll
    for (int s = 0; s < 2; ++s)
#pragma unroll
      for (int nt = 0; nt < 4; ++nt)
#pragma unroll
        for (int kk = 0; kk < 2; ++kk)
          sc[s][nt] = __builtin_amdgcn_mfma_f32_16x16x32_bf16(kf[nt][kk], aq[s][kk], sc[s][nt], 0, 0, 0);
    __builtin_amdgcn_s_setprio(0);

#pragma unroll
    for (int s = 0; s < 2; ++s) {
      float x[4][4];
#pragma unroll
      for (int nt = 0; nt < 4; ++nt)
#pragma unroll
        for (int r = 0; r < 4; ++r)
          x[nt][r] = sc[s][nt][r];
      if (usemask) {
        const int qg = q0 + s * 16 + sr;
#pragma unroll
        for (int nt = 0; nt < 4; ++nt)
#pragma unroll
          for (int r = 0; r < 4; ++r)
            x[nt][r] += mask[(size_t)qg * SEQ + t0 + nt * 16 + g * 4 + r];
      }
      // row max via max3 tree (16 -> 9 insts)
      float t1 = max3f(x[0][0], x[0][1], x[0][2]);
      float t2 = max3f(x[0][3], x[1][0], x[1][1]);
      float t3 = max3f(x[1][2], x[1][3], x[2][0]);
      float t4 = max3f(x[2][1], x[2][2], x[2][3]);
      float t5 = max3f(x[3][0], x[3][1], x[3][2]);
      float pm = fmaxf(max3f(t1, t2, t3), max3f(t4, t5, x[3][3]));
      pm = fmaxf(pm, __shfl_xor(pm, 16));
      pm = fmaxf(pm, __shfl_xor(pm, 32));
      // T13 defer-rescale (THR=8)
      if (__any(pm - m_[s] > 8.f)) {
        const float mn = fmaxf(m_[s], pm);
        const float sf = exp2f((m_[s] - mn) * L2E);
        m_[s] = mn;
        l_[s] *= sf;
        float sfb[4];
#pragma unroll
        for (int r = 0; r < 4; ++r) sfb[r] = __shfl(sf, g * 4 + r);
#pragma unroll
        for (int nd = 0; nd < 4; ++nd)
#pragma unroll
          for (int r = 0; r < 4; ++r) acc[s][nd][r] *= sfb[r];
      }
      const float mm = m_[s] * L2E;
      float rs = 0.f;
#pragma unroll
      for (int nt = 0; nt < 4; ++nt) {
        ushort4v pw;
#pragma unroll
        for (int r = 0; r < 4; ++r) {
          const float p = exp2f(__builtin_fmaf(x[nt][r], L2E, -mm));
          rs += p;
          pw[r] = f2bf_h(p);
        }
        *(ushort4v*)&Pl[w][(s * 16 + sr) * 72 + nt * 16 + g * 4] = pw;
      }
      rs += __shfl_xor(rs, 16);
      rs += __shfl_xor(rs, 32);
      l_[s] += rs;
    }

    // V^T fragments (B-operand: row d=16nd+sr, k=t=kk*32+g*8), swizzled
    short8 vf[4][2];
#pragma unroll
    for (int nd = 0; nd < 4; ++nd)
#pragma unroll
      for (int kk = 0; kk < 2; ++kk)
        vf[nd][kk] = *(const short8*)((const char*)&Vl[cur][0] +
                                      (nd * 16 + sr) * 128 + ((kk * 64 + g * 16) ^ sw));

    // O[q][d] += P[q][t] V[t][d]
    __builtin_amdgcn_s_setprio(1);
#pragma unroll
    for (int s = 0; s < 2; ++s) {
      short8 pf[2];
#pragma unroll
      for (int kk = 0; kk < 2; ++kk)
        pf[kk] = *(const short8*)&Pl[w][(s * 16 + sr) * 72 + kk * 32 + g * 8];
#pragma unroll
      for (int kk = 0; kk < 2; ++kk)
#pragma unroll
        for (int nd = 0; nd < 4; ++nd)
          acc[s][nd] = __builtin_amdgcn_mfma_f32_16x16x32_bf16(pf[kk], vf[nd][kk], acc[s][nd], 0, 0, 0);
    }
    __builtin_amdgcn_s_setprio(0);
    __syncthreads();
    cur ^= 1;
  }

  // epilogue: O rows are q_loc=g*4+r but l_ lives at lane sr=q_loc
#pragma unroll
  for (int s = 0; s < 2; ++s) {
    const float linv = 1.f / l_[s];
    float lb[4];
#pragma unroll
    for (int r = 0; r < 4; ++r) lb[r] = __shfl(linv, g * 4 + r);
#pragma unroll
    for (int nd = 0; nd < 4; ++nd)
#pragma unroll
      for (int r = 0; r < 4; ++r) {
        const int q = q0 + s * 16 + g * 4 + r;
        O[(size_t)q * 2048 + b * DM + h * DKH + nd * 16 + sr] = f2bf(acc[s][nd][r] * lb[r]);
      }
  }
}

// ---------------------------------------------------------------------------
// Launch
// ---------------------------------------------------------------------------
extern "C" void kernel_launch(void* const* d_in, const int* in_sizes, int n_in,
                              void* d_out, int out_size, void* d_ws, size_t ws_size,
                              hipStream_t stream) {
  const float* q = (const float*)d_in[0];
  const float* k = (const float*)d_in[1];
  const float* v = (const float*)d_in[2];
  const float* msk = (const float*)d_in[3];
  const float* Wq = (const float*)d_in[4];
  const float* bq = (const float*)d_in[5];
  const float* Wk = (const float*)d_in[6];
  const float* bk = (const float*)d_in[7];
  const float* Wv = (const float*)d_in[8];
  const float* bv = (const float*)d_in[9];
  const float* Wo = (const float*)d_in[10];
  const float* bo = (const float*)d_in[11];
  float* out = (float*)d_out;

  char* ws = (char*)d_ws;
  const size_t SZX = (size_t)MROWS * DM * 2;   // 8 MB bf16 activation
  const size_t SZW = (size_t)DM * DM * 2;      // 2 MB bf16 weight
  u16* qb  = (u16*)(ws + 0 * SZX);
  u16* kb  = (u16*)(ws + 1 * SZX);
  u16* vb  = (u16*)(ws + 2 * SZX);
  u16* Wqb = (u16*)(ws + 3 * SZX + 0 * SZW);
  u16* Wkb = (u16*)(ws + 3 * SZX + 1 * SZW);
  u16* Wvb = (u16*)(ws + 3 * SZX + 2 * SZW);
  u16* Wob = (u16*)(ws + 3 * SZX + 3 * SZW);
  u16* Qh  = (u16*)(ws + 3 * SZX + 4 * SZW + 0 * SZX);
  u16* Kh  = (u16*)(ws + 3 * SZX + 4 * SZW + 1 * SZX);
  u16* Vh  = (u16*)(ws + 3 * SZX + 4 * SZW + 2 * SZX);
  u16* AO  = (u16*)(ws + 3 * SZX + 4 * SZW + 3 * SZX);
  int* flag = (int*)(ws + 7 * SZX + 4 * SZW);
  u16* VTg = qb;   // reuse qb (dead after gemm_qkv)

  hipMemsetAsync(flag, 0, 4, stream);

  CvtArgs ca;
  ca.s[0] = q;  ca.d[0] = qb;  ca.n[0] = MROWS * DM; ca.scale[0] = 1.f;
  ca.s[1] = k;  ca.d[1] = kb;  ca.n[1] = MROWS * DM; ca.scale[1] = 1.f;
  ca.s[2] = v;  ca.d[2] = vb;  ca.n[2] = MROWS * DM; ca.scale[2] = 1.f;
  ca.s[3] = Wq; ca.d[3] = Wqb; ca.n[3] = DM * DM;    ca.scale[3] = 0.125f; // fold 1/sqrt(dk)
  ca.s[4] = Wk; ca.d[4] = Wkb; ca.n[4] = DM * DM;    ca.scale[4] = 1.f;
  ca.s[5] = Wv; ca.d[5] = Wvb; ca.n[5] = DM * DM;    ca.scale[5] = 1.f;
  ca.s[6] = Wo; ca.d[6] = Wob; ca.n[6] = DM * DM;    ca.scale[6] = 1.f;
  ca.s[7] = msk; ca.d[7] = nullptr; ca.n[7] = SEQ * SEQ; ca.scale[7] = 1.f;
  ca.flag = flag;
  cvt_kernel<<<dim3(1024, 8, 1), 256, 0, stream>>>(ca);

  GemmPtrs gp;
  gp.A[0] = qb; gp.W[0] = Wqb; gp.bias[0] = bq; gp.bscale[0] = 0.125f; gp.C[0] = Qh;
  gp.A[1] = kb; gp.W[1] = Wkb; gp.bias[1] = bk; gp.bscale[1] = 1.f;    gp.C[1] = Kh;
  gp.A[2] = vb; gp.W[2] = Wvb; gp.bias[2] = bv; gp.bscale[2] = 1.f;    gp.C[2] = Vh;
  gemm_qkv_kernel<<<dim3(32, 8, 3), 256, 0, stream>>>(gp, MROWS, DM, DM);

  vtrans_kernel<<<dim3(32, 32, 1), 256, 0, stream>>>(Vh, VTg);

  attn3_kernel<<<dim3(512, 1, 1), 256, 0, stream>>>(Qh, Kh, VTg, msk, flag, AO);

  gemm_f32_kernel<<<dim3(64, 8, 1), 256, 0, stream>>>(AO, Wob, bo, out, MROWS, DM, DM);
}